// Round 7
// baseline (11554.128 us; speedup 1.0000x reference)
//
#include <hip/hip_runtime.h>
#include <hip/hip_bf16.h>

// ---------------------------------------------------------------------------
// CompositePulseTransformerDecoder — MI355X (gfx950), round 7
// KV-cached incremental decode + cross-attn collapsed to constant.
// STRUCTURAL RESET: 8 blocks x 512 threads, one block per 16-row chain,
// ZERO cross-block sync (no flags/fences/partials — round-1 numerics).
// Every GEMM phase is a per-wave software-pipelined tile stream:
// 2 register banks, next tile's weight loads issued before current MFMAs,
// so each wave keeps ~8 vector loads in flight (round 1/5 sustained ~0.7).
// ---------------------------------------------------------------------------

typedef __attribute__((ext_vector_type(8))) short short8;
typedef __attribute__((ext_vector_type(4))) float f32x4;

#define EPS_ 1e-5f

__device__ __forceinline__ unsigned short f2b(float x){
  union { float f; unsigned u; } c; c.f = x;
  unsigned r = (c.u + 0x7fffu + ((c.u >> 16) & 1u)) >> 16;
  return (unsigned short)r;
}
__device__ __forceinline__ float b2f(unsigned short u){
  union { unsigned u; float f; } c; c.u = ((unsigned)u) << 16;
  return c.f;
}

// ws layout (bytes) — end 44,957,696 (< 45,744,128 proven)
#define OFF_WQKV 0ull            // 12*768*256  bf16 = 4,718,592
#define OFF_WO   4718592ull      // 12*256*256  bf16 = 1,572,864
#define OFF_L1   6291456ull      // 12*1024*256 bf16 = 6,291,456
#define OFF_L2   12582912ull     // 12*256*1024 bf16 = 6,291,456
#define OFF_SRC  18874368ull     // 128*256 f32 = 131,072
#define OFF_CC   19005440ull     // 12*128*256 bf16 = 786,432
#define OFF_KV   19791872ull     // 128*12*4*16*128 bf16 = 25,165,824

// ---------------- weight f32 -> bf16 conversion --------------------------
__global__ void k_conv(const float* __restrict__ wqkv, const float* __restrict__ wo,
                       const float* __restrict__ l1, const float* __restrict__ l2,
                       unsigned short* __restrict__ dst){
  const long long n0 = 12LL*768*256;
  const long long n1 = n0 + 12LL*256*256;
  const long long n2 = n1 + 12LL*1024*256;
  const long long n3 = n2 + 12LL*256*1024;
  for (long long idx = (long long)blockIdx.x*256 + threadIdx.x; idx < n3;
       idx += (long long)gridDim.x*256){
    float v;
    if (idx < n0) v = wqkv[idx];
    else if (idx < n1) v = wo[idx - n0];
    else if (idx < n2) v = l1[idx - n1];
    else v = l2[idx - n2];
    dst[idx] = f2b(v);
  }
}

// ---------------- src = vec @ tok_W.T + tok_b ----------------------------
__global__ void k_src(const float* __restrict__ U_real, const float* __restrict__ U_imag,
                      const float* __restrict__ tok_W, const float* __restrict__ tok_b,
                      float* __restrict__ src){
  int b = blockIdx.x, n = threadIdx.x;
  const float* w = tok_W + n*128;
  const float* ur = U_real + b*64;
  const float* ui = U_imag + b*64;
  float acc = tok_b[n];
  #pragma unroll 8
  for (int k = 0; k < 64; ++k) acc += w[k]*ur[k];
  #pragma unroll 8
  for (int k = 0; k < 64; ++k) acc += w[64+k]*ui[k];
  src[b*256+n] = acc;
}

// ------- cross-attn constant: cc[l][b] = Wo_ca @ (Wv_ca@src_b + bv) + bo --
__global__ void k_cc(const float* __restrict__ caW, const float* __restrict__ cab,
                     const float* __restrict__ caWo, const float* __restrict__ cabo,
                     const float* __restrict__ src, unsigned short* __restrict__ cc){
  int l = blockIdx.x >> 7, b = blockIdx.x & 127, t = threadIdx.x;
  __shared__ float v[256];
  const float* s = src + b*256;
  {
    const float* w = caW + ((long long)l*768 + 512 + t)*256;
    float a = cab[l*768 + 512 + t];
    #pragma unroll 8
    for (int k = 0; k < 256; ++k) a += w[k]*s[k];
    v[t] = a;
  }
  __syncthreads();
  {
    const float* w = caWo + ((long long)l*256 + t)*256;
    float a = cabo[l*256 + t];
    #pragma unroll 8
    for (int k = 0; k < 256; ++k) a += w[k]*v[k];
    cc[((long long)l*128 + b)*256 + t] = f2b(a);
  }
}

// ---------------- main decode kernel -------------------------------------
__global__ __launch_bounds__(512, 1) void k_main(
  const unsigned short* __restrict__ wqkv,   // [12][768][256] bf16
  const unsigned short* __restrict__ wo,     // [12][256][256]
  const unsigned short* __restrict__ wl1,    // [12][1024][256]
  const unsigned short* __restrict__ wl2,    // [12][256][1024]
  const float* __restrict__ bqkv, const float* __restrict__ bo_,
  const float* __restrict__ bl1,  const float* __restrict__ bl2,
  const float* __restrict__ g1, const float* __restrict__ be1,
  const float* __restrict__ g2, const float* __restrict__ be2,
  const float* __restrict__ g3, const float* __restrict__ be3,
  const unsigned short* __restrict__ cc,     // [12][128][256] bf16
  const float* __restrict__ src,             // [128][256]
  const float* __restrict__ pos,             // [17][256]
  const float* __restrict__ outW,            // [4][256]
  const float* __restrict__ outb,
  const float* __restrict__ plow, const float* __restrict__ phigh,
  unsigned short* __restrict__ kvc,          // [128][12][4][16][128] bf16 (k|v)
  float* __restrict__ out)                   // [128][16][4]
{
  __shared__ float xf[16][260];            // running x (residual source)
  __shared__ float zf[16][260];            // pre-LN scratch
  __shared__ float yf[16][260];            // y (post-LN2, FFN residual)
  __shared__ unsigned short xb[16][264];   // bf16 A-operand (x / y)
  __shared__ unsigned short qs[16][264];   // q (full 256)
  __shared__ unsigned short os[16][264];   // attn out (full 256)
  __shared__ unsigned short hb[16][1048];  // relu(lin1) full 1024

  const int tid  = threadIdx.x;
  const int w    = tid >> 6, lane = tid & 63;
  const int c    = blockIdx.x;        // chain: rows c*16 .. c*16+15
  const int mrow = lane & 15, kgrp = lane >> 4;

  // init: x = src + pos[0]
  {
    int row = tid >> 5, c8 = (tid & 31) * 8;
    const float* sp = src + (c*16 + row)*256 + c8;
    const float* pp = pos + c8;
    #pragma unroll
    for (int k = 0; k < 8; ++k){
      float v = sp[k] + pp[k];
      xf[row][c8+k] = v;
      xb[row][c8+k] = f2b(v);
    }
  }
  __syncthreads();

  for (int i = 0; i < 16; ++i){
    for (int l = 0; l < 12; ++l){
      // ===== QKV: 48 n-tiles, 6 per wave, 2-bank pipelined =====
      {
        short8 a[8];
        #pragma unroll
        for (int kc = 0; kc < 8; ++kc)
          a[kc] = *(const short8*)&xb[mrow][kc*32 + kgrp*8];
        const unsigned short* wl = wqkv + (size_t)l*196608;
        short8 b0[8], b1[8];
        {
          const unsigned short* p0 = wl + ((size_t)(w*16 + mrow))*256 + kgrp*8;
          #pragma unroll
          for (int kc = 0; kc < 8; ++kc) b0[kc] = *(const short8*)(p0 + kc*32);
        }
        #pragma unroll
        for (int j = 0; j < 6; ++j){
          if (j < 5){
            const unsigned short* pn =
                wl + ((size_t)((w + 8*(j+1))*16 + mrow))*256 + kgrp*8;
            #pragma unroll
            for (int kc = 0; kc < 8; ++kc){
              short8 v = *(const short8*)(pn + kc*32);
              if (j & 1) b0[kc] = v; else b1[kc] = v;
            }
          }
          int n_g = (w + 8*j)*16 + mrow;
          float bias = bqkv[l*768 + n_g];
          f32x4 acc = {0,0,0,0};
          #pragma unroll
          for (int kc = 0; kc < 8; ++kc)
            acc = __builtin_amdgcn_mfma_f32_16x16x32_bf16(
                a[kc], (j & 1) ? b1[kc] : b0[kc], acc, 0,0,0);
          int p = n_g >> 8, rem = n_g & 255;
          #pragma unroll
          for (int r = 0; r < 4; ++r){
            int br = kgrp*4 + r;
            float v = acc[r] + bias;
            if (p == 0){
              qs[br][rem] = f2b(v);
            } else {
              int head = rem >> 6, nl = rem & 63;
              size_t kb = ((((size_t)(c*16+br)*12 + l)*4 + head)*16 + i)*128;
              kvc[kb + (p == 2 ? 64 : 0) + nl] = f2b(v);
            }
          }
        }
      }
      __syncthreads();
      // ===== attention: 64 (row,head) tasks, 16 lanes each, 2 reps =====
      {
        #pragma unroll
        for (int rep = 0; rep < 2; ++rep){
          int task = w*8 + rep*4 + (lane >> 4);
          int row = task & 15, head = task >> 4;
          int lid = lane & 15;
          int g = c*16 + row;
          float q4[4];
          #pragma unroll
          for (int t = 0; t < 4; ++t) q4[t] = b2f(qs[row][head*64 + lid*4 + t]);
          const unsigned short* base =
              kvc + ((((size_t)g*12 + l)*4 + head)*16)*128 + lid*4;
          float sv[16];
          #pragma unroll
          for (int j = 0; j < 16; ++j){
            if (j <= i){
              const unsigned short* kp = base + j*128;
              float p = 0.f;
              #pragma unroll
              for (int t = 0; t < 4; ++t) p += q4[t]*b2f(kp[t]);
              p += __shfl_xor(p, 1);
              p += __shfl_xor(p, 2);
              p += __shfl_xor(p, 4);
              p += __shfl_xor(p, 8);
              sv[j] = p * 0.125f;               // 1/sqrt(64)
            } else sv[j] = -1e30f;
          }
          float mx = sv[0];
          #pragma unroll
          for (int j = 1; j < 16; ++j) mx = fmaxf(mx, sv[j]);
          float den = 0.f, e[16];
          #pragma unroll
          for (int j = 0; j < 16; ++j){ e[j] = __expf(sv[j]-mx); den += e[j]; }
          float rd = 1.f/den;
          float o4[4] = {0,0,0,0};
          #pragma unroll
          for (int j = 0; j < 16; ++j){
            if (j <= i){
              const unsigned short* vp = base + j*128 + 64;
              float ej = e[j];
              #pragma unroll
              for (int t = 0; t < 4; ++t) o4[t] += ej*b2f(vp[t]);
            }
          }
          #pragma unroll
          for (int t = 0; t < 4; ++t)
            os[row][head*64 + lid*4 + t] = f2b(o4[t]*rd);
        }
      }
      __syncthreads();
      // ===== Wo: 16 n-tiles, 2 per wave, pipelined; + residual -> zf =====
      {
        short8 a[8];
        #pragma unroll
        for (int kc = 0; kc < 8; ++kc)
          a[kc] = *(const short8*)&os[mrow][kc*32 + kgrp*8];
        const unsigned short* wl = wo + (size_t)l*65536;
        short8 b0[8], b1[8];
        {
          const unsigned short* p0 = wl + ((size_t)(w*2*16 + mrow))*256 + kgrp*8;
          #pragma unroll
          for (int kc = 0; kc < 8; ++kc) b0[kc] = *(const short8*)(p0 + kc*32);
        }
        #pragma unroll
        for (int u = 0; u < 2; ++u){
          if (u < 1){
            const unsigned short* pn =
                wl + ((size_t)((w*2+1)*16 + mrow))*256 + kgrp*8;
            #pragma unroll
            for (int kc = 0; kc < 8; ++kc) b1[kc] = *(const short8*)(pn + kc*32);
          }
          int n_g = (w*2+u)*16 + mrow;
          float bias = bo_[l*256 + n_g];
          f32x4 acc = {0,0,0,0};
          #pragma unroll
          for (int kc = 0; kc < 8; ++kc)
            acc = __builtin_amdgcn_mfma_f32_16x16x32_bf16(
                a[kc], u ? b1[kc] : b0[kc], acc, 0,0,0);
          #pragma unroll
          for (int r = 0; r < 4; ++r){
            int br = kgrp*4 + r;
            zf[br][n_g] = acc[r] + bias + xf[br][n_g];
          }
        }
      }
      __syncthreads();
      // ===== LN1 + cc + LN2 -> yf, xb =====
      {
        int row = tid >> 5, c8 = (lane & 31)*8;
        float t[8];
        #pragma unroll
        for (int k = 0; k < 8; ++k) t[k] = zf[row][c8+k];
        float sm = 0, sq = 0;
        #pragma unroll
        for (int k = 0; k < 8; ++k){ sm += t[k]; sq += t[k]*t[k]; }
        sm += __shfl_xor(sm,1);  sq += __shfl_xor(sq,1);
        sm += __shfl_xor(sm,2);  sq += __shfl_xor(sq,2);
        sm += __shfl_xor(sm,4);  sq += __shfl_xor(sq,4);
        sm += __shfl_xor(sm,8);  sq += __shfl_xor(sq,8);
        sm += __shfl_xor(sm,16); sq += __shfl_xor(sq,16);
        float mean = sm*(1.f/256), var = sq*(1.f/256) - mean*mean;
        float rs = rsqrtf(var + EPS_);
        const float* g1p = g1 + l*256 + c8;
        const float* b1p = be1 + l*256 + c8;
        const unsigned short* ccp = cc + ((size_t)l*128 + c*16 + row)*256 + c8;
        #pragma unroll
        for (int k = 0; k < 8; ++k)
          t[k] = (t[k]-mean)*rs*g1p[k] + b1p[k] + b2f(ccp[k]);
        sm = 0; sq = 0;
        #pragma unroll
        for (int k = 0; k < 8; ++k){ sm += t[k]; sq += t[k]*t[k]; }
        sm += __shfl_xor(sm,1);  sq += __shfl_xor(sq,1);
        sm += __shfl_xor(sm,2);  sq += __shfl_xor(sq,2);
        sm += __shfl_xor(sm,4);  sq += __shfl_xor(sq,4);
        sm += __shfl_xor(sm,8);  sq += __shfl_xor(sq,8);
        sm += __shfl_xor(sm,16); sq += __shfl_xor(sq,16);
        mean = sm*(1.f/256); var = sq*(1.f/256) - mean*mean;
        rs = rsqrtf(var + EPS_);
        const float* g2p = g2 + l*256 + c8;
        const float* b2p = be2 + l*256 + c8;
        #pragma unroll
        for (int k = 0; k < 8; ++k){
          float y = (t[k]-mean)*rs*g2p[k] + b2p[k];
          yf[row][c8+k] = y;
          xb[row][c8+k] = f2b(y);
        }
      }
      __syncthreads();
      // ===== lin1: 64 n-tiles, 8 per wave, pipelined; relu -> hb =====
      {
        short8 a[8];
        #pragma unroll
        for (int kc = 0; kc < 8; ++kc)
          a[kc] = *(const short8*)&xb[mrow][kc*32 + kgrp*8];
        const unsigned short* wl = wl1 + (size_t)l*262144;
        short8 b0[8], b1[8];
        {
          const unsigned short* p0 = wl + ((size_t)(w*16 + mrow))*256 + kgrp*8;
          #pragma unroll
          for (int kc = 0; kc < 8; ++kc) b0[kc] = *(const short8*)(p0 + kc*32);
        }
        #pragma unroll
        for (int j = 0; j < 8; ++j){
          if (j < 7){
            const unsigned short* pn =
                wl + ((size_t)((w + 8*(j+1))*16 + mrow))*256 + kgrp*8;
            #pragma unroll
            for (int kc = 0; kc < 8; ++kc){
              short8 v = *(const short8*)(pn + kc*32);
              if (j & 1) b0[kc] = v; else b1[kc] = v;
            }
          }
          int n_g = (w + 8*j)*16 + mrow;
          float bias = bl1[l*1024 + n_g];
          f32x4 acc = {0,0,0,0};
          #pragma unroll
          for (int kc = 0; kc < 8; ++kc)
            acc = __builtin_amdgcn_mfma_f32_16x16x32_bf16(
                a[kc], (j & 1) ? b1[kc] : b0[kc], acc, 0,0,0);
          #pragma unroll
          for (int r = 0; r < 4; ++r){
            float h = acc[r] + bias;
            hb[kgrp*4 + r][n_g] = f2b(h > 0.f ? h : 0.f);
          }
        }
      }
      __syncthreads();
      // ===== lin2: 2 n-tiles/wave, K=1024 in 8 chunks, pipelined =====
      {
        const unsigned short* wl = wl2 + (size_t)l*262144;
        short8 b0[8], b1[8];
        f32x4 acc0 = {0,0,0,0}, acc1 = {0,0,0,0};
        {
          const unsigned short* p0 = wl + ((size_t)(w*2*16 + mrow))*1024 + kgrp*8;
          #pragma unroll
          for (int kc = 0; kc < 8; ++kc) b0[kc] = *(const short8*)(p0 + kc*32);
        }
        #pragma unroll
        for (int ch = 0; ch < 8; ++ch){
          if (ch < 7){
            int nt = (ch+1) >> 2, kb2 = ((ch+1) & 3)*8;
            const unsigned short* pn =
                wl + ((size_t)((w*2+nt)*16 + mrow))*1024 + kb2*32 + kgrp*8;
            #pragma unroll
            for (int kc = 0; kc < 8; ++kc){
              short8 v = *(const short8*)(pn + kc*32);
              if (ch & 1) b0[kc] = v; else b1[kc] = v;
            }
          }
          int kb = (ch & 3)*8;
          short8 ah[8];
          #pragma unroll
          for (int kc = 0; kc < 8; ++kc)
            ah[kc] = *(const short8*)&hb[mrow][(kb+kc)*32 + kgrp*8];
          #pragma unroll
          for (int kc = 0; kc < 8; ++kc){
            short8 bb = (ch & 1) ? b1[kc] : b0[kc];
            if (ch >> 2)
              acc1 = __builtin_amdgcn_mfma_f32_16x16x32_bf16(ah[kc], bb, acc1, 0,0,0);
            else
              acc0 = __builtin_amdgcn_mfma_f32_16x16x32_bf16(ah[kc], bb, acc0, 0,0,0);
          }
        }
        #pragma unroll
        for (int u = 0; u < 2; ++u){
          f32x4 acc = u ? acc1 : acc0;
          int n_g = (w*2+u)*16 + mrow;
          float bias = bl2[l*256 + n_g];
          #pragma unroll
          for (int r = 0; r < 4; ++r){
            int br = kgrp*4 + r;
            zf[br][n_g] = acc[r] + bias + yf[br][n_g];
          }
        }
      }
      __syncthreads();
      // ===== LN3 -> xf, xb (+ output head @ l==11) =====
      {
        int row = tid >> 5, c8 = (lane & 31)*8;
        int g = c*16 + row;
        float t[8];
        #pragma unroll
        for (int k = 0; k < 8; ++k) t[k] = zf[row][c8+k];
        float sm = 0, sq = 0;
        #pragma unroll
        for (int k = 0; k < 8; ++k){ sm += t[k]; sq += t[k]*t[k]; }
        sm += __shfl_xor(sm,1);  sq += __shfl_xor(sq,1);
        sm += __shfl_xor(sm,2);  sq += __shfl_xor(sq,2);
        sm += __shfl_xor(sm,4);  sq += __shfl_xor(sq,4);
        sm += __shfl_xor(sm,8);  sq += __shfl_xor(sq,8);
        sm += __shfl_xor(sm,16); sq += __shfl_xor(sq,16);
        float mean = sm*(1.f/256), var = sq*(1.f/256) - mean*mean;
        float rs = rsqrtf(var + EPS_);
        const float* g3p = g3 + l*256 + c8;
        const float* b3p = be3 + l*256 + c8;
        float xn[8];
        #pragma unroll
        for (int k = 0; k < 8; ++k)
          xn[k] = (t[k]-mean)*rs*g3p[k] + b3p[k];
        if (l == 11){
          float pr[4];
          #pragma unroll
          for (int p = 0; p < 4; ++p){
            float a = 0.f;
            #pragma unroll
            for (int k = 0; k < 8; ++k) a += xn[k]*outW[p*256 + c8 + k];
            a += __shfl_xor(a,1); a += __shfl_xor(a,2);
            a += __shfl_xor(a,4); a += __shfl_xor(a,8);
            a += __shfl_xor(a,16);
            pr[p] = a;
          }
          if ((lane & 31) == 0){
            #pragma unroll
            for (int p = 0; p < 4; ++p){
              float tt = pr[p] + outb[p];
              float sg = 1.f/(1.f + __expf(-tt));
              out[((size_t)g*16 + i)*4 + p] = plow[p] + (phigh[p]-plow[p])*sg;
            }
          }
          if (i < 15){
            const float* pp = pos + (i+1)*256 + c8;
            #pragma unroll
            for (int k = 0; k < 8; ++k) xn[k] += pp[k];
          }
        }
        #pragma unroll
        for (int k = 0; k < 8; ++k){
          xf[row][c8+k] = xn[k];
          xb[row][c8+k] = f2b(xn[k]);
        }
      }
      __syncthreads();
    }
  }
}

extern "C" void kernel_launch(void* const* d_in, const int* in_sizes, int n_in,
                              void* d_out, int out_size, void* d_ws, size_t ws_size,
                              hipStream_t stream) {
  const float* U_real = (const float*)d_in[0];
  const float* U_imag = (const float*)d_in[1];
  const float* tok_W  = (const float*)d_in[2];
  const float* tok_b  = (const float*)d_in[3];
  const float* pos    = (const float*)d_in[4];
  const float* saW    = (const float*)d_in[5];
  const float* sab    = (const float*)d_in[6];
  const float* saWo   = (const float*)d_in[7];
  const float* sabo   = (const float*)d_in[8];
  const float* caW    = (const float*)d_in[9];
  const float* cab    = (const float*)d_in[10];
  const float* caWo   = (const float*)d_in[11];
  const float* cabo   = (const float*)d_in[12];
  const float* l1W    = (const float*)d_in[13];
  const float* l1b    = (const float*)d_in[14];
  const float* l2W    = (const float*)d_in[15];
  const float* l2b    = (const float*)d_in[16];
  const float* g1     = (const float*)d_in[17];
  const float* be1    = (const float*)d_in[18];
  const float* g2     = (const float*)d_in[19];
  const float* be2    = (const float*)d_in[20];
  const float* g3     = (const float*)d_in[21];
  const float* be3    = (const float*)d_in[22];
  const float* outW   = (const float*)d_in[23];
  const float* outb   = (const float*)d_in[24];
  const float* plow   = (const float*)d_in[25];
  const float* phigh  = (const float*)d_in[26];

  char* ws = (char*)d_ws;
  unsigned short* wb    = (unsigned short*)(ws + OFF_WQKV);
  float* srcb           = (float*)(ws + OFF_SRC);
  unsigned short* ccb   = (unsigned short*)(ws + OFF_CC);
  unsigned short* kvc   = (unsigned short*)(ws + OFF_KV);

  k_conv<<<dim3(4608), dim3(256), 0, stream>>>(saW, saWo, l1W, l2W, wb);
  k_src<<<dim3(128), dim3(256), 0, stream>>>(U_real, U_imag, tok_W, tok_b, srcb);
  k_cc<<<dim3(1536), dim3(256), 0, stream>>>(caW, cab, caWo, cabo, srcb, ccb);
  k_main<<<dim3(8), dim3(512), 0, stream>>>(
      wb,
      (unsigned short*)(ws + OFF_WO),
      (unsigned short*)(ws + OFF_L1),
      (unsigned short*)(ws + OFF_L2),
      sab, sabo, l1b, l2b,
      g1, be1, g2, be2, g3, be3,
      ccb, srcb, pos, outW, outb, plow, phigh,
      kvc, (float*)d_out);
}

// Round 8
// 4761.045 us; speedup vs baseline: 2.4268x; 2.4268x over previous
//
#include <hip/hip_runtime.h>
#include <hip/hip_bf16.h>

// ---------------------------------------------------------------------------
// CompositePulseTransformerDecoder — MI355X (gfx950), round 8
// SYSTOLIC LAYER PIPELINE: 48 persistent blocks = 12 layers x 4 head-slices.
// Each block only touches its own 384KB weight slice -> L2-resident forever
// (per-XCD: 6 blocks x 384KB = 2.3MB < 4MB L2). Tokens flow through layers;
// KV cache lives with its layer-block (attention fully block-local).
// All cross-block data moves via fence-free relaxed agent atomics (u64):
//   - Wo / lin2 K-split partials (packed 4x bf16)   [r6-proven protocol]
//   - x handoff between layers (packed 2x f32), single-buffered by parity
//     (safe: token loop-back orders all reuse)
//   - monotonic counter flags (fin / fA / fB), memset each launch
// No release/acquire fences anywhere -> L2 never written-back/invalidated.
// ---------------------------------------------------------------------------

typedef __attribute__((ext_vector_type(8))) short short8;
typedef __attribute__((ext_vector_type(4))) float f32x4;

#define EPS_ 1e-5f

__device__ __forceinline__ unsigned short f2b(float x){
  union { float f; unsigned u; } c; c.f = x;
  unsigned r = (c.u + 0x7fffu + ((c.u >> 16) & 1u)) >> 16;
  return (unsigned short)r;
}
__device__ __forceinline__ float b2f(unsigned short u){
  union { unsigned u; float f; } c; c.u = ((unsigned)u) << 16;
  return c.f;
}
__device__ __forceinline__ unsigned long long pack4b(const f32x4 a){
  return (unsigned long long)f2b(a[0]) |
         ((unsigned long long)f2b(a[1]) << 16) |
         ((unsigned long long)f2b(a[2]) << 32) |
         ((unsigned long long)f2b(a[3]) << 48);
}
__device__ __forceinline__ unsigned long long pack2f(float a, float b){
  union { float f; unsigned u; } x, y; x.f = a; y.f = b;
  return (unsigned long long)x.u | ((unsigned long long)y.u << 32);
}
__device__ __forceinline__ float lo_f(unsigned long long v){
  union { unsigned u; float f; } c; c.u = (unsigned)v; return c.f;
}
__device__ __forceinline__ float hi_f(unsigned long long v){
  union { unsigned u; float f; } c; c.u = (unsigned)(v >> 32); return c.f;
}

#define AL(p)    __hip_atomic_load((p),  __ATOMIC_RELAXED, __HIP_MEMORY_SCOPE_AGENT)
#define AS(p,v)  __hip_atomic_store((p), (v), __ATOMIC_RELAXED, __HIP_MEMORY_SCOPE_AGENT)

// ws layout (bytes) — total 46,010,368
#define OFF_WQKV 0ull            // 12*768*256  bf16 = 4,718,592
#define OFF_WO   4718592ull      // 12*256*256  bf16 = 1,572,864
#define OFF_L1   6291456ull      // 12*1024*256 bf16 = 6,291,456
#define OFF_L2   12582912ull     // 12*256*1024 bf16 = 6,291,456
#define OFF_SRC  18874368ull     // 128*256 f32 = 131,072
#define OFF_CC   19005440ull     // 12*128*256 bf16 = 786,432
#define OFF_KV   19791872ull     // [12][4][8][16][16][128] bf16 = 25,165,824
#define OFF_XH   44957696ull     // [2][8][16][128] u64 (f32 pairs) = 262,144
#define OFF_ZA   45219840ull     // [12][4][256][4] u64 = 393,216
#define OFF_ZB   45613056ull     // [12][4][256][4] u64 = 393,216
#define OFF_FLG  46006272ull     // 4,096: fin[12][4][8] @0, fA[12][4] @384, fB @432 (ints)

// ---------------- weight f32 -> bf16 conversion --------------------------
__global__ void k_conv(const float* __restrict__ wqkv, const float* __restrict__ wo,
                       const float* __restrict__ l1, const float* __restrict__ l2,
                       unsigned short* __restrict__ dst){
  const long long n0 = 12LL*768*256;
  const long long n1 = n0 + 12LL*256*256;
  const long long n2 = n1 + 12LL*1024*256;
  const long long n3 = n2 + 12LL*256*1024;
  for (long long idx = (long long)blockIdx.x*256 + threadIdx.x; idx < n3;
       idx += (long long)gridDim.x*256){
    float v;
    if (idx < n0) v = wqkv[idx];
    else if (idx < n1) v = wo[idx - n0];
    else if (idx < n2) v = l1[idx - n1];
    else v = l2[idx - n2];
    dst[idx] = f2b(v);
  }
}

// -------- src = vec @ tok_W.T + tok_b ;  also prime x_hand slot0 ---------
__global__ void k_src(const float* __restrict__ U_real, const float* __restrict__ U_imag,
                      const float* __restrict__ tok_W, const float* __restrict__ tok_b,
                      const float* __restrict__ pos,
                      float* __restrict__ src, float* __restrict__ xh0){
  int b = blockIdx.x, n = threadIdx.x;
  const float* w = tok_W + n*128;
  const float* ur = U_real + b*64;
  const float* ui = U_imag + b*64;
  float acc = tok_b[n];
  #pragma unroll 8
  for (int k = 0; k < 64; ++k) acc += w[k]*ur[k];
  #pragma unroll 8
  for (int k = 0; k < 64; ++k) acc += w[64+k]*ui[k];
  src[b*256+n] = acc;               // raw src (for k_cc)
  xh0[b*256+n] = acc + pos[n];      // token-0 input = src + pos[0]
}

// ------- cross-attn constant: cc[l][b] = Wo_ca @ (Wv_ca@src_b + bv) + bo --
__global__ void k_cc(const float* __restrict__ caW, const float* __restrict__ cab,
                     const float* __restrict__ caWo, const float* __restrict__ cabo,
                     const float* __restrict__ src, unsigned short* __restrict__ cc){
  int l = blockIdx.x >> 7, b = blockIdx.x & 127, t = threadIdx.x;
  __shared__ float v[256];
  const float* s = src + b*256;
  {
    const float* w = caW + ((long long)l*768 + 512 + t)*256;
    float a = cab[l*768 + 512 + t];
    #pragma unroll 8
    for (int k = 0; k < 256; ++k) a += w[k]*s[k];
    v[t] = a;
  }
  __syncthreads();
  {
    const float* w = caWo + ((long long)l*256 + t)*256;
    float a = cabo[l*256 + t];
    #pragma unroll 8
    for (int k = 0; k < 256; ++k) a += w[k]*v[k];
    cc[((long long)l*128 + b)*256 + t] = f2b(a);
  }
}

// ---------------- main systolic kernel -----------------------------------
// intra-layer sync among the 4 slice-blocks of layer l (fence-free, r6-proven)
#define PUBW(FARR) do{                                                       \
  __syncthreads();                                                           \
  if (tid == 0) AS(FARR + l*4 + h, seq);                                     \
  if (tid < 3){                                                              \
    int ho = tid + (tid >= h ? 1 : 0);                                       \
    const int* fp = FARR + l*4 + ho;                                         \
    while (AL(fp) < seq) __builtin_amdgcn_s_sleep(2);                        \
  }                                                                          \
  __syncthreads();                                                           \
}while(0)

__global__ __launch_bounds__(512, 1) void k_main(
  const unsigned short* __restrict__ wqkv,   // [12][768][256] bf16
  const unsigned short* __restrict__ wo,     // [12][256][256]
  const unsigned short* __restrict__ wl1,    // [12][1024][256]
  const unsigned short* __restrict__ wl2,    // [12][256][1024]
  const float* __restrict__ bqkv, const float* __restrict__ bo_,
  const float* __restrict__ bl1,  const float* __restrict__ bl2,
  const float* __restrict__ g1, const float* __restrict__ be1,
  const float* __restrict__ g2, const float* __restrict__ be2,
  const float* __restrict__ g3, const float* __restrict__ be3,
  const unsigned short* __restrict__ cc,     // [12][128][256] bf16
  const float* __restrict__ pos,             // [17][256]
  const float* __restrict__ outW,            // [4][256]
  const float* __restrict__ outb,
  const float* __restrict__ plow, const float* __restrict__ phigh,
  unsigned short* __restrict__ kvc,          // [12][4][8][16][16][128] bf16
  unsigned long long* __restrict__ xh,       // [2][8][16][128] u64 (f32 pairs)
  unsigned long long* __restrict__ zA,       // [12][4][256][4] u64 (4x bf16)
  unsigned long long* __restrict__ zB,       // [12][4][256][4] u64
  int* __restrict__ flags,
  float* __restrict__ out)                   // [128][16][4]
{
  __shared__ float xf[16][260];            // residual x (f32)
  __shared__ float zf[16][260];            // summed pre-LN scratch
  __shared__ float yf[16][260];            // post-LN2 (FFN residual)
  __shared__ unsigned short xb[16][264];   // bf16 A-operand (x / y)
  __shared__ unsigned short hs[16][264];   // relu(lin1) slice bf16
  __shared__ unsigned short qs[16][72];    // q slice (head h)
  __shared__ unsigned short os[16][72];    // attn out slice (head h)

  const int tid  = threadIdx.x;
  const int w    = tid >> 6, lane = tid & 63;
  const int l    = blockIdx.x >> 2;   // layer
  const int h    = blockIdx.x & 3;    // head / slice
  const int mrow = lane & 15, kgrp = lane >> 4;

  int* fin = flags;          // [12][4][8] tokens-ready counters (dest layer)
  int* fA  = flags + 384;    // [12][4]
  int* fB  = flags + 432;    // [12][4]

  for (int t = 0; t < 16; ++t){
    for (int g = 0; g < 8; ++g){
      const int seq = t*8 + g + 1;

      // ===== input: wait upstream, read x_hand[l%2][g] =====
      {
        int need = (l == 0) ? t : (t+1);
        if (need > 0 && tid < 4){
          const int* fp = fin + (l*4 + tid)*8 + g;
          while (AL(fp) < need) __builtin_amdgcn_s_sleep(2);
        }
        __syncthreads();
        int row = tid >> 5, c8 = (tid & 31)*8;
        const unsigned long long* xp =
            xh + (((size_t)(l & 1)*8 + g)*16 + row)*128 + (c8 >> 1);
        #pragma unroll
        for (int j = 0; j < 4; ++j){
          unsigned long long v = AL(xp + j);
          float f0 = lo_f(v), f1 = hi_f(v);
          xf[row][c8+2*j]   = f0;  xf[row][c8+2*j+1] = f1;
          xb[row][c8+2*j]   = f2b(f0);
          xb[row][c8+2*j+1] = f2b(f1);
        }
      }
      __syncthreads();

      // ===== QKV (head h): 12 n-tiles over 8 waves =====
      {
        short8 a[8];
        #pragma unroll
        for (int kc = 0; kc < 8; ++kc)
          a[kc] = *(const short8*)&xb[mrow][kc*32 + kgrp*8];
        const unsigned short* wl = wqkv + (size_t)l*196608;
        for (int t2 = w; t2 < 12; t2 += 8){
          int p = t2 >> 2, q4 = t2 & 3;
          int n_l = q4*16 + mrow;                 // 0..63 within head slice
          const unsigned short* wp = wl + (size_t)(p*256 + h*64 + n_l)*256 + kgrp*8;
          f32x4 acc = {0,0,0,0};
          #pragma unroll
          for (int kc = 0; kc < 8; ++kc){
            short8 b0 = *(const short8*)(wp + kc*32);
            acc = __builtin_amdgcn_mfma_f32_16x16x32_bf16(a[kc], b0, acc, 0,0,0);
          }
          float bias = bqkv[l*768 + p*256 + h*64 + n_l];
          #pragma unroll
          for (int r = 0; r < 4; ++r){
            int br = kgrp*4 + r;
            float v = acc[r] + bias;
            if (p == 0){
              qs[br][n_l] = f2b(v);
            } else {
              size_t kb = (((((size_t)l*4 + h)*8 + g)*16 + br)*16 + t)*128
                          + (p == 2 ? 64 : 0) + n_l;
              kvc[kb] = f2b(v);
            }
          }
        }
      }
      __syncthreads();

      // ===== attention (head h, block-local KV) =====
      {
        int row = w*2 + (lane >> 5);
        int lid = lane & 31;
        float q0 = b2f(qs[row][lid*2]), q1 = b2f(qs[row][lid*2+1]);
        const unsigned short* base =
            kvc + (((((size_t)l*4 + h)*8 + g)*16 + row)*16)*128 + lid*2;
        float sv[16];
        #pragma unroll
        for (int j = 0; j < 16; ++j){
          if (j <= t){
            const unsigned short* kp = base + j*128;
            float p = q0*b2f(kp[0]) + q1*b2f(kp[1]);
            p += __shfl_xor(p, 1);
            p += __shfl_xor(p, 2);
            p += __shfl_xor(p, 4);
            p += __shfl_xor(p, 8);
            p += __shfl_xor(p, 16);
            sv[j] = p * 0.125f;                 // 1/sqrt(64)
          } else sv[j] = -1e30f;
        }
        float mx = sv[0];
        #pragma unroll
        for (int j = 1; j < 16; ++j) mx = fmaxf(mx, sv[j]);
        float den = 0.f, e[16];
        #pragma unroll
        for (int j = 0; j < 16; ++j){ e[j] = __expf(sv[j]-mx); den += e[j]; }
        float rd = 1.f/den;
        float o0 = 0.f, o1 = 0.f;
        #pragma unroll
        for (int j = 0; j < 16; ++j){
          if (j <= t){
            const unsigned short* vp = base + j*128 + 64;
            o0 += e[j]*b2f(vp[0]);
            o1 += e[j]*b2f(vp[1]);
          }
        }
        os[row][lid*2]   = f2b(o0*rd);
        os[row][lid*2+1] = f2b(o1*rd);
      }
      __syncthreads();

      // ===== Wo K-split partial (N=256, K=64) -> zA u64 atomics =====
      {
        short8 a2[2];
        #pragma unroll
        for (int kc = 0; kc < 2; ++kc)
          a2[kc] = *(const short8*)&os[mrow][kc*32 + kgrp*8];
        #pragma unroll
        for (int u2 = 0; u2 < 2; ++u2){
          int n_g = (w*2+u2)*16 + mrow;
          const unsigned short* wp = wo + (size_t)l*65536 + (size_t)n_g*256 + h*64 + kgrp*8;
          f32x4 acc = {0,0,0,0};
          #pragma unroll
          for (int kc = 0; kc < 2; ++kc){
            short8 b0 = *(const short8*)(wp + kc*32);
            acc = __builtin_amdgcn_mfma_f32_16x16x32_bf16(a2[kc], b0, acc, 0,0,0);
          }
          AS(zA + ((size_t)(l*4 + h)*256 + n_g)*4 + kgrp, pack4b(acc));
        }
      }
      PUBW(fA);

      // ===== sum zA partials -> zf (+bias +residual) =====
      {
        int col = tid & 255, rq2 = tid >> 8;     // rq2: rowquads {2rq2, 2rq2+1}
        float a8[8] = {0,0,0,0,0,0,0,0};
        #pragma unroll
        for (int s4 = 0; s4 < 4; ++s4){
          const unsigned long long* bp = zA + ((size_t)(l*4 + s4)*256 + col)*4 + rq2*2;
          #pragma unroll
          for (int q = 0; q < 2; ++q){
            unsigned long long v = AL(bp + q);
            a8[q*4+0] += b2f((unsigned short)v);
            a8[q*4+1] += b2f((unsigned short)(v >> 16));
            a8[q*4+2] += b2f((unsigned short)(v >> 32));
            a8[q*4+3] += b2f((unsigned short)(v >> 48));
          }
        }
        float bias = bo_[l*256 + col];
        #pragma unroll
        for (int r = 0; r < 8; ++r){
          int row = rq2*8 + r;
          zf[row][col] = a8[r] + bias + xf[row][col];
        }
      }
      __syncthreads();

      // ===== LN1 + cc + LN2 -> yf, xb =====
      {
        int row = tid >> 5, c8 = (tid & 31)*8;
        float tt[8];
        #pragma unroll
        for (int k = 0; k < 8; ++k) tt[k] = zf[row][c8+k];
        float sm = 0, sq = 0;
        #pragma unroll
        for (int k = 0; k < 8; ++k){ sm += tt[k]; sq += tt[k]*tt[k]; }
        sm += __shfl_xor(sm,1);  sq += __shfl_xor(sq,1);
        sm += __shfl_xor(sm,2);  sq += __shfl_xor(sq,2);
        sm += __shfl_xor(sm,4);  sq += __shfl_xor(sq,4);
        sm += __shfl_xor(sm,8);  sq += __shfl_xor(sq,8);
        sm += __shfl_xor(sm,16); sq += __shfl_xor(sq,16);
        float mean = sm*(1.f/256), var = sq*(1.f/256) - mean*mean;
        float rs = rsqrtf(var + EPS_);
        const float* g1p = g1 + l*256 + c8;
        const float* b1p = be1 + l*256 + c8;
        const unsigned short* ccp = cc + ((size_t)l*128 + g*16 + row)*256 + c8;
        #pragma unroll
        for (int k = 0; k < 8; ++k)
          tt[k] = (tt[k]-mean)*rs*g1p[k] + b1p[k] + b2f(ccp[k]);
        sm = 0; sq = 0;
        #pragma unroll
        for (int k = 0; k < 8; ++k){ sm += tt[k]; sq += tt[k]*tt[k]; }
        sm += __shfl_xor(sm,1);  sq += __shfl_xor(sq,1);
        sm += __shfl_xor(sm,2);  sq += __shfl_xor(sq,2);
        sm += __shfl_xor(sm,4);  sq += __shfl_xor(sq,4);
        sm += __shfl_xor(sm,8);  sq += __shfl_xor(sq,8);
        sm += __shfl_xor(sm,16); sq += __shfl_xor(sq,16);
        mean = sm*(1.f/256); var = sq*(1.f/256) - mean*mean;
        rs = rsqrtf(var + EPS_);
        const float* g2p = g2 + l*256 + c8;
        const float* b2p = be2 + l*256 + c8;
        #pragma unroll
        for (int k = 0; k < 8; ++k){
          float y = (tt[k]-mean)*rs*g2p[k] + b2p[k];
          yf[row][c8+k] = y;
          xb[row][c8+k] = f2b(y);
        }
      }
      __syncthreads();

      // ===== lin1 N-slice (h*256..+256) + relu -> hs =====
      {
        short8 a[8];
        #pragma unroll
        for (int kc = 0; kc < 8; ++kc)
          a[kc] = *(const short8*)&xb[mrow][kc*32 + kgrp*8];
        const unsigned short* wl = wl1 + (size_t)l*262144;
        #pragma unroll
        for (int u2 = 0; u2 < 2; ++u2){
          int n_sl = (w*2+u2)*16 + mrow;
          const unsigned short* wp = wl + (size_t)(h*256 + n_sl)*256 + kgrp*8;
          f32x4 acc = {0,0,0,0};
          #pragma unroll
          for (int kc = 0; kc < 8; ++kc){
            short8 b0 = *(const short8*)(wp + kc*32);
            acc = __builtin_amdgcn_mfma_f32_16x16x32_bf16(a[kc], b0, acc, 0,0,0);
          }
          float bias = bl1[l*1024 + h*256 + n_sl];
          #pragma unroll
          for (int r = 0; r < 4; ++r){
            float hv = acc[r] + bias;
            hs[kgrp*4 + r][n_sl] = f2b(hv > 0.f ? hv : 0.f);
          }
        }
      }
      __syncthreads();

      // ===== lin2 K-split partial (K = h*256..+256) -> zB =====
      {
        short8 ah[8];
        #pragma unroll
        for (int kc = 0; kc < 8; ++kc)
          ah[kc] = *(const short8*)&hs[mrow][kc*32 + kgrp*8];
        #pragma unroll
        for (int u2 = 0; u2 < 2; ++u2){
          int n_g = (w*2+u2)*16 + mrow;
          const unsigned short* wp = wl2 + (size_t)l*262144 + (size_t)n_g*1024 + h*256 + kgrp*8;
          f32x4 acc = {0,0,0,0};
          #pragma unroll
          for (int kc = 0; kc < 8; ++kc){
            short8 b0 = *(const short8*)(wp + kc*32);
            acc = __builtin_amdgcn_mfma_f32_16x16x32_bf16(ah[kc], b0, acc, 0,0,0);
          }
          AS(zB + ((size_t)(l*4 + h)*256 + n_g)*4 + kgrp, pack4b(acc));
        }
      }
      PUBW(fB);

      // ===== sum zB partials -> zf (+bias +yf residual) =====
      {
        int col = tid & 255, rq2 = tid >> 8;
        float a8[8] = {0,0,0,0,0,0,0,0};
        #pragma unroll
        for (int s4 = 0; s4 < 4; ++s4){
          const unsigned long long* bp = zB + ((size_t)(l*4 + s4)*256 + col)*4 + rq2*2;
          #pragma unroll
          for (int q = 0; q < 2; ++q){
            unsigned long long v = AL(bp + q);
            a8[q*4+0] += b2f((unsigned short)v);
            a8[q*4+1] += b2f((unsigned short)(v >> 16));
            a8[q*4+2] += b2f((unsigned short)(v >> 32));
            a8[q*4+3] += b2f((unsigned short)(v >> 48));
          }
        }
        float bias = bl2[l*256 + col];
        #pragma unroll
        for (int r = 0; r < 8; ++r){
          int row = rq2*8 + r;
          zf[row][col] = a8[r] + bias + yf[row][col];
        }
      }
      __syncthreads();

      // ===== LN3 (+ head @ l==11) + handoff write + fin post =====
      {
        int row = tid >> 5, c8 = (tid & 31)*8;
        float tt[8];
        #pragma unroll
        for (int k = 0; k < 8; ++k) tt[k] = zf[row][c8+k];
        float sm = 0, sq = 0;
        #pragma unroll
        for (int k = 0; k < 8; ++k){ sm += tt[k]; sq += tt[k]*tt[k]; }
        sm += __shfl_xor(sm,1);  sq += __shfl_xor(sq,1);
        sm += __shfl_xor(sm,2);  sq += __shfl_xor(sq,2);
        sm += __shfl_xor(sm,4);  sq += __shfl_xor(sq,4);
        sm += __shfl_xor(sm,8);  sq += __shfl_xor(sq,8);
        sm += __shfl_xor(sm,16); sq += __shfl_xor(sq,16);
        float mean = sm*(1.f/256), var = sq*(1.f/256) - mean*mean;
        float rs = rsqrtf(var + EPS_);
        const float* g3p = g3 + l*256 + c8;
        const float* b3p = be3 + l*256 + c8;
        float xn[8];
        #pragma unroll
        for (int k = 0; k < 8; ++k)
          xn[k] = (tt[k]-mean)*rs*g3p[k] + b3p[k];
        if (l == 11){
          if (h == 0){
            float pr[4];
            #pragma unroll
            for (int p = 0; p < 4; ++p){
              float a = 0.f;
              #pragma unroll
              for (int k = 0; k < 8; ++k) a += xn[k]*outW[p*256 + c8 + k];
              a += __shfl_xor(a,1); a += __shfl_xor(a,2);
              a += __shfl_xor(a,4); a += __shfl_xor(a,8);
              a += __shfl_xor(a,16);
              pr[p] = a;
            }
            if ((tid & 31) == 0){
              int gr = g*16 + row;
              #pragma unroll
              for (int p = 0; p < 4; ++p){
                float v2 = pr[p] + outb[p];
                float sg = 1.f/(1.f + __expf(-v2));
                out[((size_t)gr*16 + t)*4 + p] = plow[p] + (phigh[p]-plow[p])*sg;
              }
            }
          }
          if (t < 15){
            const float* pp = pos + (t+1)*256 + c8;
            #pragma unroll
            for (int k = 0; k < 8; ++k) xn[k] += pp[k];
          }
        }
        bool last = (l == 11) && (t == 15);
        if (!last && ((c8 >> 6) == h)){
          unsigned long long* xp =
              xh + (((size_t)((l+1) & 1)*8 + g)*16 + row)*128 + (c8 >> 1);
          #pragma unroll
          for (int j = 0; j < 4; ++j)
            AS(xp + j, pack2f(xn[2*j], xn[2*j+1]));
        }
      }
      __syncthreads();
      if (!((l == 11) && (t == 15)) && tid == 0)
        AS(fin + ((((l+1) % 12)*4) + h)*8 + g, t+1);
    }
  }
}

extern "C" void kernel_launch(void* const* d_in, const int* in_sizes, int n_in,
                              void* d_out, int out_size, void* d_ws, size_t ws_size,
                              hipStream_t stream) {
  const float* U_real = (const float*)d_in[0];
  const float* U_imag = (const float*)d_in[1];
  const float* tok_W  = (const float*)d_in[2];
  const float* tok_b  = (const float*)d_in[3];
  const float* pos    = (const float*)d_in[4];
  const float* saW    = (const float*)d_in[5];
  const float* sab    = (const float*)d_in[6];
  const float* saWo   = (const float*)d_in[7];
  const float* sabo   = (const float*)d_in[8];
  const float* caW    = (const float*)d_in[9];
  const float* cab    = (const float*)d_in[10];
  const float* caWo   = (const float*)d_in[11];
  const float* cabo   = (const float*)d_in[12];
  const float* l1W    = (const float*)d_in[13];
  const float* l1b    = (const float*)d_in[14];
  const float* l2W    = (const float*)d_in[15];
  const float* l2b    = (const float*)d_in[16];
  const float* g1     = (const float*)d_in[17];
  const float* be1    = (const float*)d_in[18];
  const float* g2     = (const float*)d_in[19];
  const float* be2    = (const float*)d_in[20];
  const float* g3     = (const float*)d_in[21];
  const float* be3    = (const float*)d_in[22];
  const float* outW   = (const float*)d_in[23];
  const float* outb   = (const float*)d_in[24];
  const float* plow   = (const float*)d_in[25];
  const float* phigh  = (const float*)d_in[26];

  char* ws = (char*)d_ws;
  unsigned short* wb        = (unsigned short*)(ws + OFF_WQKV);
  float* srcb               = (float*)(ws + OFF_SRC);
  unsigned short* ccb       = (unsigned short*)(ws + OFF_CC);
  unsigned short* kvc       = (unsigned short*)(ws + OFF_KV);
  unsigned long long* xhb   = (unsigned long long*)(ws + OFF_XH);
  unsigned long long* zAb   = (unsigned long long*)(ws + OFF_ZA);
  unsigned long long* zBb   = (unsigned long long*)(ws + OFF_ZB);
  int* flags                = (int*)(ws + OFF_FLG);

  (void)hipMemsetAsync(ws + OFF_FLG, 0, 4096, stream);
  k_conv<<<dim3(4608), dim3(256), 0, stream>>>(saW, saWo, l1W, l2W, wb);
  k_src<<<dim3(128), dim3(256), 0, stream>>>(U_real, U_imag, tok_W, tok_b, pos,
                                             srcb, (float*)xhb);
  k_cc<<<dim3(1536), dim3(256), 0, stream>>>(caW, cab, caWo, cabo, srcb, ccb);
  k_main<<<dim3(48), dim3(512), 0, stream>>>(
      wb,
      (unsigned short*)(ws + OFF_WO),
      (unsigned short*)(ws + OFF_L1),
      (unsigned short*)(ws + OFF_L2),
      sab, sabo, l1b, l2b,
      g1, be1, g2, be2, g3, be3,
      ccb, pos, outW, outb, plow, phigh,
      kvc, xhb, zAb, zBb, flags, (float*)d_out);
}